// Round 16
// baseline (121.924 us; speedup 1.0000x reference)
//
#include <hip/hip_runtime.h>
#include <hip/hip_bf16.h>

typedef __hip_bfloat16 bf16;
typedef __attribute__((ext_vector_type(8))) short short8;
typedef __attribute__((ext_vector_type(4))) short short4v;
typedef __attribute__((ext_vector_type(4))) float f32x4;

#define BB 2
#define NN 2048
#define CC 1024
#define HH 16
#define DD 64
#define MM (BB*NN)     // 4096
#define QKVN 3072
#define LOG2E 1.44269504088896340736f

__device__ __forceinline__ void glds16(const void* g, void* l) {
    __builtin_amdgcn_global_load_lds((const __attribute__((address_space(1))) void*)g,
                                     (__attribute__((address_space(3))) void*)l, 16, 0, 0);
}
__device__ __forceinline__ short pkbf(float x) { bf16 t = (bf16)x; return *(short*)&t; }
__device__ __forceinline__ float b2f(short s) {
    return __uint_as_float(((unsigned)(unsigned short)s) << 16);
}

// ---------------------------------------------------------------------------
// Fused prep: blocks [0,4096) convert hs fp32->bf16; blocks [4096,8192)
// transpose Wq/Wk/Wv/Wo fp32[K][N] -> bf16 Wt[N][K].
// ---------------------------------------------------------------------------
__global__ __launch_bounds__(256) void prep_fused(const float* __restrict__ hs,
                                                  const float* __restrict__ W0,
                                                  const float* __restrict__ W1,
                                                  const float* __restrict__ W2,
                                                  const float* __restrict__ W3,
                                                  bf16* __restrict__ hsb,
                                                  bf16* __restrict__ Wtqkv,
                                                  bf16* __restrict__ Wto) {
    __shared__ float t[32][33];
    const int bid = blockIdx.x;
    if (bid < 4096) {
        const int i = bid * 256 + threadIdx.x;
        float4 v = ((const float4*)hs)[i];
        short4v s;
        s.x = pkbf(v.x); s.y = pkbf(v.y); s.z = pkbf(v.z); s.w = pkbf(v.w);
        *((short4v*)hsb + i) = s;
    } else {
        const int b2 = bid - 4096;
        const int z = b2 >> 10;                  // 1024 blocks per weight
        const float* W = z == 0 ? W0 : (z == 1 ? W1 : (z == 2 ? W2 : W3));
        bf16* dst = z < 3 ? Wtqkv + (size_t)z * CC * CC : Wto;
        const int bx = b2 & 31, by = (b2 >> 5) & 31;
        const int tx = threadIdx.x & 31, ty = threadIdx.x >> 5;   // (32,8)
        const int x0 = bx * 32, y0 = by * 32;
        #pragma unroll
        for (int i = 0; i < 4; ++i)
            t[ty + i * 8][tx] = W[(size_t)(y0 + ty + i * 8) * CC + x0 + tx];
        __syncthreads();
        #pragma unroll
        for (int i = 0; i < 4; ++i)
            dst[(size_t)(x0 + ty + i * 8) * CC + y0 + tx] = (bf16)t[tx][ty + i * 8];
    }
}

// ---------------------------------------------------------------------------
// bf16 MFMA GEMM v4 (unchanged): triple-buffered, depth-2 prefetch, counted
// vmcnt(4) + raw s_barrier per K-step.
// MODE 1: QKV epilogue (RoPE+log2e on q/k cols; V transposed to VtOut)
// MODE 2: fp32 output (out-projection)
// ---------------------------------------------------------------------------
template<int Nn, int MODE>
__global__ __launch_bounds__(256) void gemm4(const bf16* __restrict__ A,
                                             const bf16* __restrict__ Bt,
                                             void* __restrict__ Cout,
                                             const float* __restrict__ cosp,
                                             const float* __restrict__ sinp,
                                             bf16* __restrict__ VtOut) {
    __shared__ __align__(16) bf16 As[3][128 * 32];   // 24 KB
    __shared__ __align__(16) bf16 Bs[3][128 * 32];   // 24 KB
    const int tid = threadIdx.x, lane = tid & 63, wid = tid >> 6;
    const int wr = wid >> 1, wc = wid & 1, l16 = lane & 15, lg = lane >> 4;
    const int n0 = blockIdx.x * 128, m0 = blockIdx.y * 128;

    f32x4 acc[4][4];
    #pragma unroll
    for (int i = 0; i < 4; ++i)
        #pragma unroll
        for (int j = 0; j < 4; ++j) acc[i][j] = {0.f, 0.f, 0.f, 0.f};

    const int issue0 = wid * 2;
    const int sr0 = (issue0 * 1024 + lane * 16) >> 6;
    const int sc0 = ((issue0 * 1024 + lane * 16) & 63) >> 1;
    const int sr1 = ((issue0 + 1) * 1024 + lane * 16) >> 6;
    const int sc1 = (((issue0 + 1) * 1024 + lane * 16) & 63) >> 1;

    auto stage = [&](int k0, int bufi) {        // 4 glds16 per thread/wave
        glds16(&A [(size_t)(m0 + sr0) * 1024 + k0 + sc0], (char*)&As[bufi][0] + issue0 * 1024);
        glds16(&Bt[(size_t)(n0 + sr0) * 1024 + k0 + sc0], (char*)&Bs[bufi][0] + issue0 * 1024);
        glds16(&A [(size_t)(m0 + sr1) * 1024 + k0 + sc1], (char*)&As[bufi][0] + (issue0 + 1) * 1024);
        glds16(&Bt[(size_t)(n0 + sr1) * 1024 + k0 + sc1], (char*)&Bs[bufi][0] + (issue0 + 1) * 1024);
    };

    stage(0, 0);
    stage(32, 1);
    int cur = 0, sb = 2;                        // read buffer / stage buffer
    for (int t = 0; t < 32; ++t) {
        asm volatile("s_waitcnt vmcnt(4)" ::: "memory");   // stage(t) retired; t+1 in flight
        __builtin_amdgcn_s_barrier();                      // publish stage(t) cross-wave
        __builtin_amdgcn_sched_barrier(0);                 // fence ds_read hoisting
        if (t + 2 < 32) stage((t + 2) * 32, sb);
        short8 af[4], bfr[4];
        #pragma unroll
        for (int i = 0; i < 4; ++i) af[i]  = *(const short8*)((char*)&As[cur][0] + (wr * 64 + i * 16 + l16) * 64 + lg * 16);
        #pragma unroll
        for (int j = 0; j < 4; ++j) bfr[j] = *(const short8*)((char*)&Bs[cur][0] + (wc * 64 + j * 16 + l16) * 64 + lg * 16);
        #pragma unroll
        for (int i = 0; i < 4; ++i)
            #pragma unroll
            for (int j = 0; j < 4; ++j)
                acc[i][j] = __builtin_amdgcn_mfma_f32_16x16x32_bf16(af[i], bfr[j], acc[i][j], 0, 0, 0);
        cur = (cur == 2) ? 0 : cur + 1;
        sb  = (sb  == 2) ? 0 : sb  + 1;
    }

    if (MODE == 1 && n0 >= 2 * CC) {
        // V region: write transposed Vt[b][h][d][n], 8B stores
        #pragma unroll
        for (int i = 0; i < 4; ++i) {
            const int row0 = m0 + wr * 64 + i * 16 + lg * 4;
            const int bb = row0 >> 11, nn_ = row0 & (NN - 1);
            #pragma unroll
            for (int j = 0; j < 4; ++j) {
                const int col = n0 - 2 * CC + wc * 64 + j * 16 + l16;
                const int hh = col >> 6, d = col & 63;
                short4v s4;
                #pragma unroll
                for (int r = 0; r < 4; ++r) s4[r] = pkbf(acc[i][j][r]);
                *(short4v*)&VtOut[((size_t)(bb * HH + hh) * DD + d) * NN + nn_] = s4;
            }
        }
    } else if (MODE == 1) {
        // q/k region: RoPE (cos[d]==cos[d+32]); q scaled by D^-0.5*log2e
        const float qs = (n0 < CC) ? 0.125f * LOG2E : 1.0f;
        bf16* Cb = (bf16*)Cout;
        #pragma unroll
        for (int i = 0; i < 4; ++i)
            #pragma unroll
            for (int r = 0; r < 4; ++r) {
                const int row = m0 + wr * 64 + i * 16 + lg * 4 + r;
                #pragma unroll
                for (int j = 0; j < 2; ++j) {
                    const int d = j * 16 + l16;          // < 32
                    const float cv = cosp[(size_t)row * DD + d];
                    const float sv = sinp[(size_t)row * DD + d];
                    const float x1 = acc[i][j][r];
                    const float x2 = acc[i][j + 2][r];
                    const size_t cbase = (size_t)row * QKVN + n0 + wc * 64 + j * 16 + l16;
                    Cb[cbase]      = (bf16)((x1 * cv - x2 * sv) * qs);
                    Cb[cbase + 32] = (bf16)((x2 * cv + x1 * sv) * qs);
                }
            }
    } else {
        float* Cf = (float*)Cout;
        #pragma unroll
        for (int i = 0; i < 4; ++i)
            #pragma unroll
            for (int r = 0; r < 4; ++r) {
                const int row = m0 + wr * 64 + i * 16 + lg * 4 + r;
                #pragma unroll
                for (int j = 0; j < 4; ++j)
                    Cf[(size_t)row * Nn + n0 + wc * 64 + j * 16 + l16] = acc[i][j][r];
            }
    }
}

// ---------------------------------------------------------------------------
// Flash attention v9: QBLK=128 (4 waves x 32 q-rows via qm=2), KVBLK=64,
// 3-way split-KV, v6's 2-buffer __syncthreads staging (proven), swapped QK^T,
// in-reg P->PV, shuffle-free softmax, defer-rescale. K/V fragments reused 2x
// across qm; two independent chains per wave hide MFMA/exp latency.
// Wave-uniform skip of fully-masked tiles (k0 > wq0+31) — also prevents the
// exp(0) bug when a part's first tile is fully masked.
// Grid: 1536 = 16 qslots x 3 parts x 32 bh.
// ---------------------------------------------------------------------------
__global__ __launch_bounds__(256) void flash_mfma9(const bf16* __restrict__ QKV,
                                                   const bf16* __restrict__ Vt,
                                                   bf16* __restrict__ PartA,
                                                   bf16* __restrict__ PartB,
                                                   bf16* __restrict__ PartC,
                                                   float2* __restrict__ Mlb) {
    __shared__ __align__(16) bf16 Ks[2][4096];
    __shared__ __align__(16) bf16 Vs[2][4096];
    const int tid = threadIdx.x, lane = tid & 63, wid = tid >> 6;
    const int l16 = lane & 15, lg = lane >> 4;
    const int bid = blockIdx.x;                 // 1536 = 48 slots x 32 bh
    const int bh = bid & 31;
    const int slot = bid >> 5;                  // 0..47
    const int qt = 15 - slot / 3;               // heavy-first, 128-row q-tiles
    const int part = slot % 3;
    const int h = bh & (HH - 1), b = bh >> 4;
    const int wq0 = qt * 128 + wid * 32;        // wave's first q-row (owns 32)
    const int nkt = 2 * qt + 2;
    const int t0 = (part * nkt) / 3;
    const int cnt = ((part + 1) * nkt) / 3 - t0;

    const bf16* Kbase = QKV + (size_t)b * NN * QKVN + CC + h * DD;  // + k*QKVN
    const bf16* Vbase = Vt + (size_t)(b * HH + h) * DD * NN;        // + d*NN + k

    // Q fragments: rows wq0 + qm*16 + l16, two K=32 chunks
    short8 qf[2][2];
    #pragma unroll
    for (int qm = 0; qm < 2; ++qm)
        #pragma unroll
        for (int ch = 0; ch < 2; ++ch)
            qf[qm][ch] = *(const short8*)&QKV[(size_t)(b * NN + wq0 + qm * 16 + l16) * QKVN
                                              + h * DD + ch * 32 + lg * 8];

    f32x4 o[4][2];
    #pragma unroll
    for (int dn = 0; dn < 4; ++dn)
        #pragma unroll
        for (int qm = 0; qm < 2; ++qm) o[dn][qm] = {0.f, 0.f, 0.f, 0.f};
    float mx[2] = {-1e30f, -1e30f}, ls[2] = {0.f, 0.f};

    const int a0 = (wid * 2) * 1024 + lane * 16, a1 = a0 + 1024;
    const int r0 = a0 >> 7, c0 = ((a0 & 127) ^ ((r0 & 7) << 4)) >> 1;
    const int r1 = a1 >> 7, c1 = ((a1 & 127) ^ ((r1 & 7) << 4)) >> 1;
    const bf16* kp0 = Kbase + (size_t)(t0 * 64 + r0) * QKVN + c0;
    const bf16* kp1 = Kbase + (size_t)(t0 * 64 + r1) * QKVN + c1;
    const bf16* vp0 = Vbase + (size_t)r0 * NN + t0 * 64 + c0;
    const bf16* vp1 = Vbase + (size_t)r1 * NN + t0 * 64 + c1;
    char* ldsK = (char*)&Ks[0][0] + wid * 2048;
    char* ldsV = (char*)&Vs[0][0] + wid * 2048;

    auto stage = [&](int par) {
        glds16(kp0, ldsK + par * 8192);
        glds16(kp1, ldsK + par * 8192 + 1024);
        glds16(vp0, ldsV + par * 8192);
        glds16(vp1, ldsV + par * 8192 + 1024);
        kp0 += 64 * QKVN; kp1 += 64 * QKVN; vp0 += 64; vp1 += 64;
    };

    if (cnt > 0) stage(0);
    for (int i = 0; i < cnt; ++i) {
        __syncthreads();                 // drains stage(i) vmcnt; prev buf reads done
        if (i + 1 < cnt) stage((i + 1) & 1);
        const int cur = i & 1;
        const int kt = t0 + i;
        const int k0 = kt * 64;

        if (k0 <= wq0 + 31) {            // wave-uniform: tile has unmasked elems
            // ---- S^T = K Q^T : k rows, q cols; K frag reused across qm ----
            f32x4 st[4][2];
            #pragma unroll
            for (int kc = 0; kc < 4; ++kc)
                #pragma unroll
                for (int qm = 0; qm < 2; ++qm) st[kc][qm] = {0.f, 0.f, 0.f, 0.f};
            __builtin_amdgcn_s_setprio(1);
            #pragma unroll
            for (int kc = 0; kc < 4; ++kc) {
                const int row = kc * 16 + l16;
                const char* rb = (const char*)&Ks[cur][0] + row * 128;
                const int sw = (row & 7) << 4;
                short8 kf0 = *(const short8*)(rb + ((lg * 16) ^ sw));
                short8 kf1 = *(const short8*)(rb + ((64 + lg * 16) ^ sw));
                #pragma unroll
                for (int qm = 0; qm < 2; ++qm) {
                    st[kc][qm] = __builtin_amdgcn_mfma_f32_16x16x32_bf16(kf0, qf[qm][0], st[kc][qm], 0, 0, 0);
                    st[kc][qm] = __builtin_amdgcn_mfma_f32_16x16x32_bf16(kf1, qf[qm][1], st[kc][qm], 0, 0, 0);
                }
            }
            __builtin_amdgcn_s_setprio(0);

            if (k0 + 63 > wq0) {         // diagonal-ish: element-wise causal mask
                #pragma unroll
                for (int kc = 0; kc < 4; ++kc)
                    #pragma unroll
                    for (int qm = 0; qm < 2; ++qm)
                        #pragma unroll
                        for (int r = 0; r < 4; ++r)
                            if (k0 + kc * 16 + lg * 4 + r > wq0 + qm * 16 + l16)
                                st[kc][qm][r] = -1e30f;
            }

            // ---- online softmax per qm: per-lane max; shuffles only on rescale ----
            #pragma unroll
            for (int qm = 0; qm < 2; ++qm) {
                float rm = fmaxf(fmaxf(st[0][qm][0], st[0][qm][1]), fmaxf(st[0][qm][2], st[0][qm][3]));
                #pragma unroll
                for (int kc = 1; kc < 4; ++kc)
                    rm = fmaxf(rm, fmaxf(fmaxf(st[kc][qm][0], st[kc][qm][1]),
                                         fmaxf(st[kc][qm][2], st[kc][qm][3])));
                if (__any(rm > mx[qm] + 8.0f)) {
                    float wmx = fmaxf(rm, __shfl_xor(rm, 16, 64));
                    wmx = fmaxf(wmx, __shfl_xor(wmx, 32, 64));
                    const float mn = fmaxf(mx[qm], wmx);
                    const float sc = __builtin_amdgcn_exp2f(mx[qm] - mn);
                    ls[qm] *= sc;
                    #pragma unroll
                    for (int dn = 0; dn < 4; ++dn) {
                        o[dn][qm][0] *= sc; o[dn][qm][1] *= sc;
                        o[dn][qm][2] *= sc; o[dn][qm][3] *= sc;
                    }
                    mx[qm] = mn;
                }
                float rs = 0.f;
                #pragma unroll
                for (int kc = 0; kc < 4; ++kc)
                    #pragma unroll
                    for (int r = 0; r < 4; ++r) {
                        const float p = __builtin_amdgcn_exp2f(st[kc][qm][r] - mx[qm]);
                        st[kc][qm][r] = p; rs += p;
                    }
                ls[qm] += rs;
            }

            // ---- O^T += V^T P^T ; V frag reused across qm ----
            __builtin_amdgcn_s_setprio(1);
            #pragma unroll
            for (int kc = 0; kc < 4; ++kc) {
                short4v pf[2];
                #pragma unroll
                for (int qm = 0; qm < 2; ++qm) {
                    pf[qm][0] = pkbf(st[kc][qm][0]); pf[qm][1] = pkbf(st[kc][qm][1]);
                    pf[qm][2] = pkbf(st[kc][qm][2]); pf[qm][3] = pkbf(st[kc][qm][3]);
                }
                #pragma unroll
                for (int dn = 0; dn < 4; ++dn) {
                    const int row = dn * 16 + l16;
                    short4v vf = *(const short4v*)((const char*)&Vs[cur][0] + row * 128
                                                   + ((kc * 32 + lg * 8) ^ ((row & 7) << 4)));
                    o[dn][0] = __builtin_amdgcn_mfma_f32_16x16x16bf16_1k(vf, pf[0], o[dn][0], 0, 0, 0);
                    o[dn][1] = __builtin_amdgcn_mfma_f32_16x16x16bf16_1k(vf, pf[1], o[dn][1], 0, 0, 0);
                }
            }
            __builtin_amdgcn_s_setprio(0);
        }
    }

    // ---- epilogue: reduce ls per qm, store partials (zeros if nothing done) ----
    #pragma unroll
    for (int qm = 0; qm < 2; ++qm) {
        float l = ls[qm];
        l += __shfl_xor(l, 16, 64);
        l += __shfl_xor(l, 32, 64);
        const int grow = b * NN + wq0 + qm * 16 + l16;
        if (lg == 0) Mlb[((size_t)(part * MM) + grow) * HH + h] = make_float2(mx[qm], l);
        bf16* dst = part == 0 ? PartA : (part == 1 ? PartB : PartC);
        const size_t rowb = (size_t)grow * CC + h * DD;
        #pragma unroll
        for (int dn = 0; dn < 4; ++dn) {
            short4v s4;
            s4[0] = pkbf(o[dn][qm][0]); s4[1] = pkbf(o[dn][qm][1]);
            s4[2] = pkbf(o[dn][qm][2]); s4[3] = pkbf(o[dn][qm][3]);
            *(short4v*)&dst[rowb + dn * 16 + lg * 4] = s4;
        }
    }
}

// ---------------------------------------------------------------------------
// Combine the three KV-parts.
// ---------------------------------------------------------------------------
__global__ __launch_bounds__(256) void merge3(const bf16* __restrict__ pa,
                                              const bf16* __restrict__ pb,
                                              const bf16* __restrict__ pc,
                                              const float2* __restrict__ ml,
                                              bf16* __restrict__ outp) {
    const int idx = blockIdx.x * 256 + threadIdx.x;    // 524288 total
    const int row = idx >> 7;
    const int h = (idx & 127) >> 3;
    const float2 a  = ml[(size_t)row * HH + h];
    const float2 b_ = ml[((size_t)MM + row) * HH + h];
    const float2 c  = ml[((size_t)2 * MM + row) * HH + h];
    const float M = fmaxf(fmaxf(a.x, b_.x), c.x);
    const float w0 = (a.y  > 0.f) ? __builtin_amdgcn_exp2f(a.x  - M) : 0.f;
    const float w1 = (b_.y > 0.f) ? __builtin_amdgcn_exp2f(b_.x - M) : 0.f;
    const float w2 = (c.y  > 0.f) ? __builtin_amdgcn_exp2f(c.x  - M) : 0.f;
    const float inv = 1.f / (a.y * w0 + b_.y * w1 + c.y * w2);
    const float f0 = w0 * inv, f1 = w1 * inv, f2 = w2 * inv;
    const size_t off = (size_t)idx * 8;
    short8 va = *(const short8*)(pa + off);
    short8 vb = *(const short8*)(pb + off);
    short8 vc = *(const short8*)(pc + off);
    short8 ov;
    #pragma unroll
    for (int e = 0; e < 8; ++e)
        ov[e] = pkbf(b2f(va[e]) * f0 + b2f(vb[e]) * f1 + b2f(vc[e]) * f2);
    *(short8*)(outp + off) = ov;
}

// ---------------------------------------------------------------------------
extern "C" void kernel_launch(void* const* d_in, const int* in_sizes, int n_in,
                              void* d_out, int out_size, void* d_ws, size_t ws_size,
                              hipStream_t stream) {
    const float* hs   = (const float*)d_in[0];
    const float* cosp = (const float*)d_in[1];
    const float* sinp = (const float*)d_in[2];
    const float* Wq   = (const float*)d_in[3];
    const float* Wk   = (const float*)d_in[4];
    const float* Wv   = (const float*)d_in[5];
    const float* Wo   = (const float*)d_in[6];
    float* out = (float*)d_out;

    char* ws = (char*)d_ws;
    bf16* hsb   = (bf16*)(ws);                    //  8 MB [4096][1024]
    bf16* Wtqkv = (bf16*)(ws + (8  << 20));       //  6 MB [3072][1024]
    bf16* Wto   = (bf16*)(ws + (14 << 20));       //  2 MB [1024][1024]
    bf16* QKV   = (bf16*)(ws + (16 << 20));       // 24 MB [4096][3072] (q,k cols used)
    bf16* Vtb   = (bf16*)(ws + (40 << 20));       //  8 MB [2][16][64][2048]
    bf16* Abuf  = hsb;                            // alias: hs consumed by QKV GEMM
    float2* Mlb = (float2*)Wtqkv;                 // alias: Wtqkv dead after QKV GEMM (1.5 MB)
    bf16* PartB = (bf16*)out;                     // d_out as scratch until out-GEMM
    bf16* PartC = (bf16*)out + (size_t)MM * CC;   // second half of d_out

    prep_fused<<<8192, 256, 0, stream>>>(hs, Wq, Wk, Wv, Wo, hsb, Wtqkv, Wto);

    gemm4<QKVN, 1><<<dim3(QKVN / 128, MM / 128), 256, 0, stream>>>(
        hsb, Wtqkv, QKV, cosp, sinp, Vtb);

    flash_mfma9<<<1536, 256, 0, stream>>>(QKV, Vtb, Abuf, PartB, PartC, Mlb);

    merge3<<<2048, 256, 0, stream>>>(Abuf, PartB, PartC, Mlb, Abuf);

    gemm4<CC, 2><<<dim3(CC / 128, MM / 128), 256, 0, stream>>>(
        Abuf, Wto, out, nullptr, nullptr, nullptr);
}

// Round 17
// 116.132 us; speedup vs baseline: 1.0499x; 1.0499x over previous
//
#include <hip/hip_runtime.h>
#include <hip/hip_bf16.h>

typedef __hip_bfloat16 bf16;
typedef __attribute__((ext_vector_type(8))) short short8;
typedef __attribute__((ext_vector_type(4))) short short4v;
typedef __attribute__((ext_vector_type(4))) float f32x4;

#define BB 2
#define NN 2048
#define CC 1024
#define HH 16
#define DD 64
#define MM (BB*NN)     // 4096
#define QKVN 3072
#define LOG2E 1.44269504088896340736f

__device__ __forceinline__ void glds16(const void* g, void* l) {
    __builtin_amdgcn_global_load_lds((const __attribute__((address_space(1))) void*)g,
                                     (__attribute__((address_space(3))) void*)l, 16, 0, 0);
}
__device__ __forceinline__ short pkbf(float x) { bf16 t = (bf16)x; return *(short*)&t; }
__device__ __forceinline__ float b2f(short s) {
    return __uint_as_float(((unsigned)(unsigned short)s) << 16);
}

// ---------------------------------------------------------------------------
// Fused prep: blocks [0,4096) convert hs fp32->bf16; blocks [4096,8192)
// transpose Wq/Wk/Wv/Wo fp32[K][N] -> bf16 Wt[N][K].
// ---------------------------------------------------------------------------
__global__ __launch_bounds__(256) void prep_fused(const float* __restrict__ hs,
                                                  const float* __restrict__ W0,
                                                  const float* __restrict__ W1,
                                                  const float* __restrict__ W2,
                                                  const float* __restrict__ W3,
                                                  bf16* __restrict__ hsb,
                                                  bf16* __restrict__ Wtqkv,
                                                  bf16* __restrict__ Wto) {
    __shared__ float t[32][33];
    const int bid = blockIdx.x;
    if (bid < 4096) {
        const int i = bid * 256 + threadIdx.x;
        float4 v = ((const float4*)hs)[i];
        short4v s;
        s.x = pkbf(v.x); s.y = pkbf(v.y); s.z = pkbf(v.z); s.w = pkbf(v.w);
        *((short4v*)hsb + i) = s;
    } else {
        const int b2 = bid - 4096;
        const int z = b2 >> 10;                  // 1024 blocks per weight
        const float* W = z == 0 ? W0 : (z == 1 ? W1 : (z == 2 ? W2 : W3));
        bf16* dst = z < 3 ? Wtqkv + (size_t)z * CC * CC : Wto;
        const int bx = b2 & 31, by = (b2 >> 5) & 31;
        const int tx = threadIdx.x & 31, ty = threadIdx.x >> 5;   // (32,8)
        const int x0 = bx * 32, y0 = by * 32;
        #pragma unroll
        for (int i = 0; i < 4; ++i)
            t[ty + i * 8][tx] = W[(size_t)(y0 + ty + i * 8) * CC + x0 + tx];
        __syncthreads();
        #pragma unroll
        for (int i = 0; i < 4; ++i)
            dst[(size_t)(x0 + ty + i * 8) * CC + y0 + tx] = (bf16)t[tx][ty + i * 8];
    }
}

// ---------------------------------------------------------------------------
// bf16 MFMA GEMM v4 (unchanged): 128x128 tile, triple-buffered, depth-2
// prefetch, counted vmcnt(4) + raw s_barrier per K-step. QKV epilogue
// (RoPE+log2e on q/k cols; V transposed to VtOut).
// ---------------------------------------------------------------------------
__global__ __launch_bounds__(256) void gemm4qkv(const bf16* __restrict__ A,
                                                const bf16* __restrict__ Bt,
                                                bf16* __restrict__ Cb,
                                                const float* __restrict__ cosp,
                                                const float* __restrict__ sinp,
                                                bf16* __restrict__ VtOut) {
    __shared__ __align__(16) bf16 As[3][128 * 32];   // 24 KB
    __shared__ __align__(16) bf16 Bs[3][128 * 32];   // 24 KB
    const int tid = threadIdx.x, lane = tid & 63, wid = tid >> 6;
    const int wr = wid >> 1, wc = wid & 1, l16 = lane & 15, lg = lane >> 4;
    const int n0 = blockIdx.x * 128, m0 = blockIdx.y * 128;

    f32x4 acc[4][4];
    #pragma unroll
    for (int i = 0; i < 4; ++i)
        #pragma unroll
        for (int j = 0; j < 4; ++j) acc[i][j] = {0.f, 0.f, 0.f, 0.f};

    const int issue0 = wid * 2;
    const int sr0 = (issue0 * 1024 + lane * 16) >> 6;
    const int sc0 = ((issue0 * 1024 + lane * 16) & 63) >> 1;
    const int sr1 = ((issue0 + 1) * 1024 + lane * 16) >> 6;
    const int sc1 = (((issue0 + 1) * 1024 + lane * 16) & 63) >> 1;

    auto stage = [&](int k0, int bufi) {        // 4 glds16 per thread
        glds16(&A [(size_t)(m0 + sr0) * 1024 + k0 + sc0], (char*)&As[bufi][0] + issue0 * 1024);
        glds16(&Bt[(size_t)(n0 + sr0) * 1024 + k0 + sc0], (char*)&Bs[bufi][0] + issue0 * 1024);
        glds16(&A [(size_t)(m0 + sr1) * 1024 + k0 + sc1], (char*)&As[bufi][0] + (issue0 + 1) * 1024);
        glds16(&Bt[(size_t)(n0 + sr1) * 1024 + k0 + sc1], (char*)&Bs[bufi][0] + (issue0 + 1) * 1024);
    };

    stage(0, 0);
    stage(32, 1);
    int cur = 0, sb = 2;
    for (int t = 0; t < 32; ++t) {
        asm volatile("s_waitcnt vmcnt(4)" ::: "memory");   // stage(t) retired; t+1 in flight
        __builtin_amdgcn_s_barrier();
        __builtin_amdgcn_sched_barrier(0);
        if (t + 2 < 32) stage((t + 2) * 32, sb);
        short8 af[4], bfr[4];
        #pragma unroll
        for (int i = 0; i < 4; ++i) af[i]  = *(const short8*)((char*)&As[cur][0] + (wr * 64 + i * 16 + l16) * 64 + lg * 16);
        #pragma unroll
        for (int j = 0; j < 4; ++j) bfr[j] = *(const short8*)((char*)&Bs[cur][0] + (wc * 64 + j * 16 + l16) * 64 + lg * 16);
        #pragma unroll
        for (int i = 0; i < 4; ++i)
            #pragma unroll
            for (int j = 0; j < 4; ++j)
                acc[i][j] = __builtin_amdgcn_mfma_f32_16x16x32_bf16(af[i], bfr[j], acc[i][j], 0, 0, 0);
        cur = (cur == 2) ? 0 : cur + 1;
        sb  = (sb  == 2) ? 0 : sb  + 1;
    }

    if (n0 >= 2 * CC) {
        // V region: write transposed Vt[b][h][d][n], 8B stores
        #pragma unroll
        for (int i = 0; i < 4; ++i) {
            const int row0 = m0 + wr * 64 + i * 16 + lg * 4;
            const int bb = row0 >> 11, nn_ = row0 & (NN - 1);
            #pragma unroll
            for (int j = 0; j < 4; ++j) {
                const int col = n0 - 2 * CC + wc * 64 + j * 16 + l16;
                const int hh = col >> 6, d = col & 63;
                short4v s4;
                #pragma unroll
                for (int r = 0; r < 4; ++r) s4[r] = pkbf(acc[i][j][r]);
                *(short4v*)&VtOut[((size_t)(bb * HH + hh) * DD + d) * NN + nn_] = s4;
            }
        }
    } else {
        // q/k region: RoPE (cos[d]==cos[d+32]); q scaled by D^-0.5*log2e
        const float qs = (n0 < CC) ? 0.125f * LOG2E : 1.0f;
        #pragma unroll
        for (int i = 0; i < 4; ++i)
            #pragma unroll
            for (int r = 0; r < 4; ++r) {
                const int row = m0 + wr * 64 + i * 16 + lg * 4 + r;
                #pragma unroll
                for (int j = 0; j < 2; ++j) {
                    const int d = j * 16 + l16;          // < 32
                    const float cv = cosp[(size_t)row * DD + d];
                    const float sv = sinp[(size_t)row * DD + d];
                    const float x1 = acc[i][j][r];
                    const float x2 = acc[i][j + 2][r];
                    const size_t cbase = (size_t)row * QKVN + n0 + wc * 64 + j * 16 + l16;
                    Cb[cbase]      = (bf16)((x1 * cv - x2 * sv) * qs);
                    Cb[cbase + 32] = (bf16)((x2 * cv + x1 * sv) * qs);
                }
            }
    }
}

// ---------------------------------------------------------------------------
// Out-projection GEMM v5: 64x128 tile (BM=64, BN=128, BK=32) -> 512 blocks
// (2/CU vs 1/CU at 128x128). Same skeleton: 3 buffers, depth-2 prefetch,
// counted vmcnt(3) (3 loads/thread/stage: A 1, B 2) + raw s_barrier.
// LDS 36 KB. Waves 2x2: wave (wr,wc) owns M rows [wr*32,+32), N cols
// [wc*64,+64); acc[2][4]. fp32 output.
// ---------------------------------------------------------------------------
__global__ __launch_bounds__(256) void gemm4o(const bf16* __restrict__ A,
                                              const bf16* __restrict__ Bt,
                                              float* __restrict__ Cf) {
    __shared__ __align__(16) bf16 As[3][64 * 32];    // 12 KB
    __shared__ __align__(16) bf16 Bs[3][128 * 32];   // 24 KB
    const int tid = threadIdx.x, lane = tid & 63, wid = tid >> 6;
    const int wr = wid >> 1, wc = wid & 1, l16 = lane & 15, lg = lane >> 4;
    const int n0 = blockIdx.x * 128, m0 = blockIdx.y * 64;

    f32x4 acc[2][4];
    #pragma unroll
    for (int i = 0; i < 2; ++i)
        #pragma unroll
        for (int j = 0; j < 4; ++j) acc[i][j] = {0.f, 0.f, 0.f, 0.f};

    // A: 1 load/thread — row tid>>2, elem col (tid&3)*8; dest tid*16 B (linear)
    const int asr = tid >> 2, asc = (tid & 3) * 8;
    // B: 2 loads/thread — gemm4's 128x32 pattern
    const int issue0 = wid * 2;
    const int sr0 = (issue0 * 1024 + lane * 16) >> 6;
    const int sc0 = ((issue0 * 1024 + lane * 16) & 63) >> 1;
    const int sr1 = ((issue0 + 1) * 1024 + lane * 16) >> 6;
    const int sc1 = (((issue0 + 1) * 1024 + lane * 16) & 63) >> 1;

    auto stage = [&](int k0, int bufi) {        // 3 glds16 per thread
        glds16(&A [(size_t)(m0 + asr) * 1024 + k0 + asc], (char*)&As[bufi][0] + tid * 16);
        glds16(&Bt[(size_t)(n0 + sr0) * 1024 + k0 + sc0], (char*)&Bs[bufi][0] + issue0 * 1024);
        glds16(&Bt[(size_t)(n0 + sr1) * 1024 + k0 + sc1], (char*)&Bs[bufi][0] + (issue0 + 1) * 1024);
    };

    stage(0, 0);
    stage(32, 1);
    int cur = 0, sb = 2;
    for (int t = 0; t < 32; ++t) {
        asm volatile("s_waitcnt vmcnt(3)" ::: "memory");   // stage(t) retired; t+1 in flight
        __builtin_amdgcn_s_barrier();
        __builtin_amdgcn_sched_barrier(0);
        if (t + 2 < 32) stage((t + 2) * 32, sb);
        short8 af[2], bfr[4];
        #pragma unroll
        for (int i = 0; i < 2; ++i) af[i]  = *(const short8*)((char*)&As[cur][0] + (wr * 32 + i * 16 + l16) * 64 + lg * 16);
        #pragma unroll
        for (int j = 0; j < 4; ++j) bfr[j] = *(const short8*)((char*)&Bs[cur][0] + (wc * 64 + j * 16 + l16) * 64 + lg * 16);
        #pragma unroll
        for (int i = 0; i < 2; ++i)
            #pragma unroll
            for (int j = 0; j < 4; ++j)
                acc[i][j] = __builtin_amdgcn_mfma_f32_16x16x32_bf16(af[i], bfr[j], acc[i][j], 0, 0, 0);
        cur = (cur == 2) ? 0 : cur + 1;
        sb  = (sb  == 2) ? 0 : sb  + 1;
    }

    #pragma unroll
    for (int i = 0; i < 2; ++i)
        #pragma unroll
        for (int r = 0; r < 4; ++r) {
            const int row = m0 + wr * 32 + i * 16 + lg * 4 + r;
            #pragma unroll
            for (int j = 0; j < 4; ++j)
                Cf[(size_t)row * CC + n0 + wc * 64 + j * 16 + l16] = acc[i][j][r];
        }
}

// ---------------------------------------------------------------------------
// Flash attention v6 (r14 version, verbatim — measured 46.7 us): 3-way
// split-KV, K+V LDS-staged (2-buffer, swizzled), swapped QK^T, in-reg P->PV,
// shuffle-free common softmax path, defer-rescale.
// ---------------------------------------------------------------------------
__global__ __launch_bounds__(256) void flash_mfma6(const bf16* __restrict__ QKV,
                                                   const bf16* __restrict__ Vt,
                                                   bf16* __restrict__ PartA,
                                                   bf16* __restrict__ PartB,
                                                   bf16* __restrict__ PartC,
                                                   float2* __restrict__ Mlb) {
    __shared__ __align__(16) bf16 Ks[2][4096];
    __shared__ __align__(16) bf16 Vs[2][4096];
    const int tid = threadIdx.x, lane = tid & 63, wid = tid >> 6;
    const int l16 = lane & 15, lg = lane >> 4;
    const int bid = blockIdx.x;                 // 3072 = 96 slots x 32 bh
    const int bh = bid & 31;                    // bid%8 spreads bh across XCDs
    const int slot = bid >> 5;                  // 0..95
    const int qt = 31 - slot / 3;               // heavy-first
    const int part = slot % 3;
    const int h = bh & (HH - 1), b = bh >> 4;
    const int wq0 = qt * 64 + wid * 16;
    const int nkt = qt + 1;
    const int t0 = (part * nkt) / 3;
    const int cnt = ((part + 1) * nkt) / 3 - t0;
    const int grow = b * NN + wq0 + l16;        // global q-row of lane's column

    const bf16* Kbase = QKV + (size_t)b * NN * QKVN + CC + h * DD;  // + k*QKVN
    const bf16* Vbase = Vt + (size_t)(b * HH + h) * DD * NN;        // + d*NN + k

    short8 qf[2];
    #pragma unroll
    for (int ch = 0; ch < 2; ++ch)
        qf[ch] = *(const short8*)&QKV[(size_t)grow * QKVN + h * DD + ch * 32 + lg * 8];

    f32x4 o[4];
    #pragma unroll
    for (int dn = 0; dn < 4; ++dn) o[dn] = {0.f, 0.f, 0.f, 0.f};
    float mx = -1e30f, ls = 0.f;                // ls = per-lane partial sum

    const int a0 = (wid * 2) * 1024 + lane * 16, a1 = a0 + 1024;
    const int r0 = a0 >> 7, c0 = ((a0 & 127) ^ ((r0 & 7) << 4)) >> 1;
    const int r1 = a1 >> 7, c1 = ((a1 & 127) ^ ((r1 & 7) << 4)) >> 1;
    const bf16* kp0 = Kbase + (size_t)(t0 * 64 + r0) * QKVN + c0;
    const bf16* kp1 = Kbase + (size_t)(t0 * 64 + r1) * QKVN + c1;
    const bf16* vp0 = Vbase + (size_t)r0 * NN + t0 * 64 + c0;
    const bf16* vp1 = Vbase + (size_t)r1 * NN + t0 * 64 + c1;
    char* ldsK = (char*)&Ks[0][0] + wid * 2048;
    char* ldsV = (char*)&Vs[0][0] + wid * 2048;

    auto stage = [&](int par) {
        glds16(kp0, ldsK + par * 8192);
        glds16(kp1, ldsK + par * 8192 + 1024);
        glds16(vp0, ldsV + par * 8192);
        glds16(vp1, ldsV + par * 8192 + 1024);
        kp0 += 64 * QKVN; kp1 += 64 * QKVN; vp0 += 64; vp1 += 64;
    };

    if (cnt > 0) stage(0);
    for (int i = 0; i < cnt; ++i) {
        __syncthreads();                 // drains stage(i) vmcnt; buf[(i+1)&1] reads done
        if (i + 1 < cnt) stage((i + 1) & 1);
        const int cur = i & 1;
        const int kt = t0 + i;
        const int k0 = kt * 64;

        // ---- S^T = K Q^T : k rows, q cols ----
        f32x4 st[4];
        #pragma unroll
        for (int kc = 0; kc < 4; ++kc) st[kc] = {0.f, 0.f, 0.f, 0.f};
        __builtin_amdgcn_s_setprio(1);
        #pragma unroll
        for (int kc = 0; kc < 4; ++kc) {
            const int row = kc * 16 + l16;
            const char* rb = (const char*)&Ks[cur][0] + row * 128;
            const int sw = (row & 7) << 4;
            short8 kf0 = *(const short8*)(rb + ((lg * 16) ^ sw));
            short8 kf1 = *(const short8*)(rb + ((64 + lg * 16) ^ sw));
            st[kc] = __builtin_amdgcn_mfma_f32_16x16x32_bf16(kf0, qf[0], st[kc], 0, 0, 0);
            st[kc] = __builtin_amdgcn_mfma_f32_16x16x32_bf16(kf1, qf[1], st[kc], 0, 0, 0);
        }
        __builtin_amdgcn_s_setprio(0);

        if (kt == qt) {                  // diagonal tile: causal mask
            #pragma unroll
            for (int kc = 0; kc < 4; ++kc)
                #pragma unroll
                for (int r = 0; r < 4; ++r)
                    if (k0 + kc * 16 + lg * 4 + r > wq0 + l16) st[kc][r] = -1e30f;
        }

        // ---- online softmax: per-lane max; shuffles only on rescale ----
        float rm = fmaxf(fmaxf(st[0][0], st[0][1]), fmaxf(st[0][2], st[0][3]));
        #pragma unroll
        for (int kc = 1; kc < 4; ++kc)
            rm = fmaxf(rm, fmaxf(fmaxf(st[kc][0], st[kc][1]), fmaxf(st[kc][2], st[kc][3])));
        if (__any(rm > mx + 8.0f)) {     // rare: full row-max + rescale
            float wmx = fmaxf(rm, __shfl_xor(rm, 16, 64));
            wmx = fmaxf(wmx, __shfl_xor(wmx, 32, 64));
            const float mn = fmaxf(mx, wmx);
            const float sc = __builtin_amdgcn_exp2f(mx - mn);
            ls *= sc;
            #pragma unroll
            for (int dn = 0; dn < 4; ++dn) {
                o[dn][0] *= sc; o[dn][1] *= sc; o[dn][2] *= sc; o[dn][3] *= sc;
            }
            mx = mn;
        }
        float rs = 0.f;
        #pragma unroll
        for (int kc = 0; kc < 4; ++kc)
            #pragma unroll
            for (int r = 0; r < 4; ++r) {
                const float p = __builtin_amdgcn_exp2f(st[kc][r] - mx);
                st[kc][r] = p; rs += p;
            }
        ls += rs;                        // per-lane partial; reduced in epilogue

        // ---- O^T += V^T P^T ----
        __builtin_amdgcn_s_setprio(1);
        #pragma unroll
        for (int kc = 0; kc < 4; ++kc) {
            short4v pf;
            pf[0] = pkbf(st[kc][0]); pf[1] = pkbf(st[kc][1]);
            pf[2] = pkbf(st[kc][2]); pf[3] = pkbf(st[kc][3]);
            #pragma unroll
            for (int dn = 0; dn < 4; ++dn) {
                const int row = dn * 16 + l16;
                short4v vf = *(const short4v*)((const char*)&Vs[cur][0] + row * 128
                                               + ((kc * 32 + lg * 8) ^ ((row & 7) << 4)));
                o[dn] = __builtin_amdgcn_mfma_f32_16x16x16bf16_1k(vf, pf, o[dn], 0, 0, 0);
            }
        }
        __builtin_amdgcn_s_setprio(0);
    }

    // ---- epilogue: reduce ls across the 4 lanes sharing a q-row, store partials ----
    ls += __shfl_xor(ls, 16, 64);
    ls += __shfl_xor(ls, 32, 64);
    if (lg == 0) Mlb[((size_t)(part * MM) + grow) * HH + h] = make_float2(mx, ls);
    bf16* dst = part == 0 ? PartA : (part == 1 ? PartB : PartC);
    const size_t rowb = (size_t)grow * CC + h * DD;
    #pragma unroll
    for (int dn = 0; dn < 4; ++dn) {
        short4v s4;
        s4[0] = pkbf(o[dn][0]); s4[1] = pkbf(o[dn][1]);
        s4[2] = pkbf(o[dn][2]); s4[3] = pkbf(o[dn][3]);
        *(short4v*)&dst[rowb + dn * 16 + lg * 4] = s4;
    }
}

// ---------------------------------------------------------------------------
// Combine the three KV-parts.
// ---------------------------------------------------------------------------
__global__ __launch_bounds__(256) void merge3(const bf16* __restrict__ pa,
                                              const bf16* __restrict__ pb,
                                              const bf16* __restrict__ pc,
                                              const float2* __restrict__ ml,
                                              bf16* __restrict__ outp) {
    const int idx = blockIdx.x * 256 + threadIdx.x;    // 524288 total
    const int row = idx >> 7;
    const int h = (idx & 127) >> 3;
    const float2 a  = ml[(size_t)row * HH + h];
    const float2 b_ = ml[((size_t)MM + row) * HH + h];
    const float2 c  = ml[((size_t)2 * MM + row) * HH + h];
    const float M = fmaxf(fmaxf(a.x, b_.x), c.x);
    const float w0 = (a.y  > 0.f) ? __builtin_amdgcn_exp2f(a.x  - M) : 0.f;
    const float w1 = (b_.y > 0.f) ? __builtin_amdgcn_exp2f(b_.x - M) : 0.f;
    const float w2 = (c.y  > 0.f) ? __builtin_amdgcn_exp2f(c.x  - M) : 0.f;
    const float inv = 1.f / (a.y * w0 + b_.y * w1 + c.y * w2);
    const float f0 = w0 * inv, f1 = w1 * inv, f2 = w2 * inv;
    const size_t off = (size_t)idx * 8;
    short8 va = *(const short8*)(pa + off);
    short8 vb = *(const short8*)(pb + off);
    short8 vc = *(const short8*)(pc + off);
    short8 ov;
    #pragma unroll
    for (int e = 0; e < 8; ++e)
        ov[e] = pkbf(b2f(va[e]) * f0 + b2f(vb[e]) * f1 + b2f(vc[e]) * f2);
    *(short8*)(outp + off) = ov;
}

// ---------------------------------------------------------------------------
extern "C" void kernel_launch(void* const* d_in, const int* in_sizes, int n_in,
                              void* d_out, int out_size, void* d_ws, size_t ws_size,
                              hipStream_t stream) {
    const float* hs   = (const float*)d_in[0];
    const float* cosp = (const float*)d_in[1];
    const float* sinp = (const float*)d_in[2];
    const float* Wq   = (const float*)d_in[3];
    const float* Wk   = (const float*)d_in[4];
    const float* Wv   = (const float*)d_in[5];
    const float* Wo   = (const float*)d_in[6];
    float* out = (float*)d_out;

    char* ws = (char*)d_ws;
    bf16* hsb   = (bf16*)(ws);                    //  8 MB [4096][1024]
    bf16* Wtqkv = (bf16*)(ws + (8  << 20));       //  6 MB [3072][1024]
    bf16* Wto   = (bf16*)(ws + (14 << 20));       //  2 MB [1024][1024]
    bf16* QKV   = (bf16*)(ws + (16 << 20));       // 24 MB [4096][3072] (q,k cols used)
    bf16* Vtb   = (bf16*)(ws + (40 << 20));       //  8 MB [2][16][64][2048]
    bf16* Abuf  = hsb;                            // alias: hs consumed by QKV GEMM
    float2* Mlb = (float2*)Wtqkv;                 // alias: Wtqkv dead after QKV GEMM (1.5 MB)
    bf16* PartB = (bf16*)out;                     // d_out as scratch until out-GEMM
    bf16* PartC = (bf16*)out + (size_t)MM * CC;   // second half of d_out

    prep_fused<<<8192, 256, 0, stream>>>(hs, Wq, Wk, Wv, Wo, hsb, Wtqkv, Wto);

    gemm4qkv<<<dim3(QKVN / 128, MM / 128), 256, 0, stream>>>(
        hsb, Wtqkv, QKV, cosp, sinp, Vtb);

    flash_mfma6<<<3072, 256, 0, stream>>>(QKV, Vtb, Abuf, PartB, PartC, Mlb);

    merge3<<<2048, 256, 0, stream>>>(Abuf, PartB, PartC, Mlb, Abuf);

    gemm4o<<<dim3(CC / 128, MM / 64), 256, 0, stream>>>(Abuf, Wto, out);
}